// Round 1
// baseline (9509.098 us; speedup 1.0000x reference)
//
#include <hip/hip_runtime.h>
#include <math.h>

#define Tt  100
#define H1  2560
#define HID 5120
#define H2  1024

typedef float f32x4 __attribute__((ext_vector_type(4)));

// Workspace layout (float offsets)
enum {
  OFF_POST = 0,      // 16
  OFF_SP   = 16,     // 16
  OFF_M1X  = 32,     // 16
  OFF_M1Y  = 48,     // 16
  OFF_SPR  = 64,     // 16
  OFF_KIN  = 80,     // 32 (unused now; kept for layout stability)
  OFF_L1   = 112,    // 2560  (16B aligned: 112*4=448)
  OFF_L2   = 2672,   // 1024
  OFF_KG   = 3696,   // 256
  OFF_HA   = 3952,   // 5120
  OFF_HB   = 9072,   // 5120
};

__global__ void k_init(const float* __restrict__ m1_0, const float* __restrict__ h0,
                       float* __restrict__ ws) {
  int i = blockIdx.x * blockDim.x + threadIdx.x;
  if (i < 16) { ws[OFF_POST + i] = m1_0[i]; ws[OFF_SP + i] = m1_0[i]; }
  if (i < HID) ws[OFF_HA + i] = h0[i];
}

// Fused: innovation update for step t-1 (if do_F) + prior/KGain-input + L1 for step t.
// Every block redundantly computes the tiny 16-wide state chain into LDS (deterministic,
// identical across blocks); only block 0 writes the global state/output. Then each block
// computes its 256 rows of l1 = relu(W1 @ kin + b1).
__global__ void k_front(const float* __restrict__ Fm, const float* __restrict__ Hm,
                        const float* __restrict__ y, float* __restrict__ ws,
                        float* __restrict__ out,
                        const float* __restrict__ W1, const float* __restrict__ b1,
                        int t, int do_F) {
  __shared__ float s_post[16], s_sp[16], s_m1x[16], s_spr[16], s_d[16], s_yv[16], s_dy[16];
  __shared__ float s_kin[32];
  const int tid = threadIdx.x;
  float* post = ws + OFF_POST;
  float* sp   = ws + OFF_SP;
  float* m1x  = ws + OFF_M1X;
  float* m1y  = ws + OFF_M1Y;
  float* spr  = ws + OFF_SPR;
  const float* KG = ws + OFF_KG;
  const bool w = (blockIdx.x == 0);

  if (do_F) {
    if (tid < 16) s_dy[tid] = y[tid * Tt + (t - 1)] - m1y[tid];
    __syncthreads();
    if (tid < 16) {
      float acc = m1x[tid];
      #pragma unroll
      for (int j = 0; j < 16; j++) acc = fmaf(KG[tid * 16 + j], s_dy[j], acc);
      s_post[tid] = acc;
      float sv = spr[tid];
      s_sp[tid] = sv;
      if (w) { post[tid] = acc; out[tid * Tt + (t - 1)] = acc; sp[tid] = sv; }
    }
    __syncthreads();
  } else {
    if (tid < 16) { s_post[tid] = post[tid]; s_sp[tid] = sp[tid]; }
    __syncthreads();
  }
  if (t >= Tt) return;

  if (tid < 16) {
    float a = 0.f, b = 0.f;
    #pragma unroll
    for (int j = 0; j < 16; j++) {
      a = fmaf(Fm[tid * 16 + j], s_post[j], a);
      b = fmaf(Fm[tid * 16 + j], s_sp[j], b);
    }
    s_m1x[tid] = a; s_spr[tid] = b;
    if (w) { m1x[tid] = a; spr[tid] = b; }
  }
  __syncthreads();
  if (tid < 16) {
    float my = 0.f, ob = 0.f;
    #pragma unroll
    for (int j = 0; j < 16; j++) {
      my = fmaf(Hm[tid * 16 + j], s_m1x[j], my);
      ob = fmaf(Hm[tid * 16 + j], s_spr[j], ob);
    }
    if (w) m1y[tid] = my;
    s_yv[tid] = y[tid * Tt + t] - ob;
    s_d[tid] = s_post[tid] - s_sp[tid];
  }
  __syncthreads();
  if (tid < 16) {
    float nd = 0.f, ny = 0.f;
    #pragma unroll
    for (int j = 0; j < 16; j++) { nd += s_d[j] * s_d[j]; ny += s_yv[j] * s_yv[j]; }
    nd = fmaxf(sqrtf(nd), 1e-12f);
    ny = fmaxf(sqrtf(ny), 1e-12f);
    s_kin[tid]      = s_d[tid] / nd;
    s_kin[16 + tid] = s_yv[tid] / ny;
  }
  __syncthreads();

  // L1 phase: row r = blockIdx.x*256 + tid
  const int r = blockIdx.x * 256 + tid;
  const float4* row = (const float4*)(W1 + (size_t)r * 32);
  float acc = b1[r];
  #pragma unroll
  for (int j = 0; j < 8; j++) {
    float4 wv = row[j];
    acc = fmaf(wv.x, s_kin[4 * j + 0], acc);
    acc = fmaf(wv.y, s_kin[4 * j + 1], acc);
    acc = fmaf(wv.z, s_kin[4 * j + 2], acc);
    acc = fmaf(wv.w, s_kin[4 * j + 3], acc);
  }
  ws[OFF_L1 + r] = fmaxf(acc, 0.f);
}

__device__ __forceinline__ float block_reduce_256(float v, float* sdata) {
  const int tid = threadIdx.x;
  #pragma unroll
  for (int off = 32; off > 0; off >>= 1) v += __shfl_down(v, off, 64);
  __syncthreads();
  if ((tid & 63) == 0) sdata[tid >> 6] = v;
  __syncthreads();
  float r = (tid < 4) ? sdata[tid] : 0.f;
  r += __shfl_down(r, 2, 64);
  r += __shfl_down(r, 1, 64);
  return r;  // valid on tid 0
}

// Fused GRU: block i computes 3 W_ih-row dots + 3 W_hh-row dots + cell update.
// W_hh (315 MB, can never fit L3) is loaded NON-TEMPORAL so the 180 MB of
// reusable weights (W_ih, W2, W1, W3) stay resident in the 256 MB Infinity Cache
// across the 100 sequential steps.
__global__ void k_gru(const float* __restrict__ W_ih, const float* __restrict__ b_ih,
                      const float* __restrict__ W_hh, const float* __restrict__ b_hh,
                      const float* __restrict__ l1, const float* __restrict__ h_in,
                      float* __restrict__ h_out) {
  const int i = blockIdx.x;
  const int tid = threadIdx.x;
  __shared__ float sdata[4];
  const float4* l1v = (const float4*)l1;
  const float4* hv  = (const float4*)h_in;
  float p[6];
  #pragma unroll
  for (int g = 0; g < 3; g++) {
    const float4* row = (const float4*)(W_ih + (size_t)(i + g * HID) * H1);
    float acc = 0.f;
    for (int j = tid; j < H1 / 4; j += 256) {
      float4 w = row[j], x = l1v[j];
      acc = fmaf(w.x, x.x, fmaf(w.y, x.y, fmaf(w.z, x.z, fmaf(w.w, x.w, acc))));
    }
    p[g] = acc;
  }
  #pragma unroll
  for (int g = 0; g < 3; g++) {
    const f32x4* row = (const f32x4*)(W_hh + (size_t)(i + g * HID) * HID);
    float acc = 0.f;
    for (int j = tid; j < HID / 4; j += 256) {
      f32x4 w = __builtin_nontemporal_load(row + j);   // nt: stream, don't cache
      float4 x = hv[j];
      acc = fmaf(w.x, x.x, fmaf(w.y, x.y, fmaf(w.z, x.z, fmaf(w.w, x.w, acc))));
    }
    p[3 + g] = acc;
  }
  float s[6];
  #pragma unroll
  for (int k = 0; k < 6; k++) s[k] = block_reduce_256(p[k], sdata);
  if (tid == 0) {
    float ir = s[0] + b_ih[i], iz = s[1] + b_ih[i + HID], inn = s[2] + b_ih[i + 2 * HID];
    float hr = s[3] + b_hh[i], hz = s[4] + b_hh[i + HID], hn  = s[5] + b_hh[i + 2 * HID];
    float r = 1.f / (1.f + expf(-(ir + hr)));
    float z = 1.f / (1.f + expf(-(iz + hz)));
    float nn = tanhf(inn + r * hn);
    h_out[i] = (1.f - z) * nn + z * h_in[i];
  }
}

__global__ void k_l2(const float* __restrict__ W2, const float* __restrict__ b2,
                     const float* __restrict__ h, float* __restrict__ l2) {
  const int j = blockIdx.x;
  const int tid = threadIdx.x;
  __shared__ float sdata[4];
  const float4* row = (const float4*)(W2 + (size_t)j * HID);
  const float4* xv  = (const float4*)h;
  float acc = 0.f;
  for (int k = tid; k < HID / 4; k += 256) {
    float4 w = row[k], x = xv[k];
    acc = fmaf(w.x, x.x, fmaf(w.y, x.y, fmaf(w.z, x.z, fmaf(w.w, x.w, acc))));
  }
  float s = block_reduce_256(acc, sdata);
  if (tid == 0) l2[j] = fmaxf(s + b2[j], 0.f);
}

__global__ void k_kg(const float* __restrict__ W3, const float* __restrict__ b3,
                     const float* __restrict__ l2, float* __restrict__ KG) {
  const int k = blockIdx.x;
  const int tid = threadIdx.x;
  const float4* row = (const float4*)(W3 + (size_t)k * H2);
  const float4* xv  = (const float4*)l2;
  float acc = 0.f;
  for (int j = tid; j < H2 / 4; j += 64) {
    float4 w = row[j], x = xv[j];
    acc = fmaf(w.x, x.x, fmaf(w.y, x.y, fmaf(w.z, x.z, fmaf(w.w, x.w, acc))));
  }
  #pragma unroll
  for (int off = 32; off > 0; off >>= 1) acc += __shfl_down(acc, off, 64);
  if (tid == 0) KG[k] = acc + b3[k];
}

extern "C" void kernel_launch(void* const* d_in, const int* in_sizes, int n_in,
                              void* d_out, int out_size, void* d_ws, size_t ws_size,
                              hipStream_t stream) {
  const float* y    = (const float*)d_in[0];
  const float* Fm   = (const float*)d_in[1];
  const float* Hm   = (const float*)d_in[2];
  const float* m1_0 = (const float*)d_in[3];
  const float* h0   = (const float*)d_in[4];
  const float* W1   = (const float*)d_in[5];
  const float* b1   = (const float*)d_in[6];
  const float* W_ih = (const float*)d_in[7];
  const float* b_ih = (const float*)d_in[8];
  const float* W_hh = (const float*)d_in[9];
  const float* b_hh = (const float*)d_in[10];
  const float* W2   = (const float*)d_in[11];
  const float* b2   = (const float*)d_in[12];
  const float* W3   = (const float*)d_in[13];
  const float* b3   = (const float*)d_in[14];
  float* out = (float*)d_out;
  float* ws  = (float*)d_ws;

  k_init<<<(HID + 255) / 256, 256, 0, stream>>>(m1_0, h0, ws);

  for (int t = 0; t < Tt; t++) {
    k_front<<<H1 / 256, 256, 0, stream>>>(Fm, Hm, y, ws, out, W1, b1, t, t > 0 ? 1 : 0);
    const float* h_in = ws + ((t & 1) ? OFF_HB : OFF_HA);
    float* h_out      = ws + ((t & 1) ? OFF_HA : OFF_HB);
    k_gru<<<HID, 256, 0, stream>>>(W_ih, b_ih, W_hh, b_hh, ws + OFF_L1, h_in, h_out);
    k_l2<<<H2, 256, 0, stream>>>(W2, b2, h_out, ws + OFF_L2);
    k_kg<<<256, 64, 0, stream>>>(W3, b3, ws + OFF_L2, ws + OFF_KG);
  }
  // Final innovation update (writes output column T-1)
  k_front<<<1, 256, 0, stream>>>(Fm, Hm, y, ws, out, W1, b1, Tt, 1);
}